// Round 8
// baseline (304.587 us; speedup 1.0000x reference)
//
#include <hip/hip_runtime.h>

// SoftTriple loss, MI355X. B=256, E=512, C=8192, K=10.
// Round 8: h round-trip + ce_kernel ELIMINATED. The gemm epilogue folds
// cross-entropy directly: logits = 10*h are bounded (|x|<~50) so
// logsumexp needs NO max shift in fp32; each block atomicAdds its
// 8-class partial sum of exp(10h) per batch row into sumexp[256]
// (256 distinct addresses/block, 1024 adds/address over ~35us -> no
// contention), and the single block owning label[b]'s class applies the
// margin + stores lab_logit[b]. final: ce_b = log(sumexp[b])-lab_logit[b].
// GEMM core / prep / staging swizzle are the verified r7 code, untouched.
// ws layout (bytes):
//   [0, 83886080)        w  bf16 [81920][512]  (normalized, compact)
//   [83886080, 84148224) At bf16 [16][256][32] (k-chunked emb)
//   [84148224, 84181000) gram_part float[8192]   (at +84148224+... see below)
//   [84181248, 84182272) sumexp  float[256]
//   [84182272, 84183296) lab_logit float[256]

typedef __bf16 bf16;
typedef bf16 bf16x8 __attribute__((ext_vector_type(8)));
typedef float f32x4 __attribute__((ext_vector_type(4)));

#define NCLASS 8192
#define KC 10
#define EDIM 512
#define BATCH 256
#define BK 64

__device__ inline void load_lds16(const void* g, void* l) {
    __builtin_amdgcn_global_load_lds(
        (const __attribute__((address_space(1))) void*)g,
        (__attribute__((address_space(3))) void*)l, 16, 0, 0);
}

// ---------------- kernel 1: normalize + gram + compact bf16 write ---------
// blocks [0,8192): prep. [8192,8256): emb->At. block 8256: zero sumexp.
__global__ __launch_bounds__(256) void prep_kernel(
    const float* __restrict__ fc, bf16* __restrict__ w,
    float* __restrict__ gram_part,
    const float* __restrict__ e, bf16* __restrict__ At,
    float* __restrict__ sumexp)
{
    __shared__ float rows[KC * EDIM];   // 20 KB
    __shared__ float s_invn[KC];
    __shared__ float s_wsum[4];
    const int t = threadIdx.x;

    if (blockIdx.x >= NCLASS) {
        if (blockIdx.x == NCLASS + 64) {      // zero the CE accumulator
            sumexp[t] = 0.0f;
            return;
        }
        // ---- emb fp32 -> bf16, k-chunk transposed: At[k>>5][row][k&31] ----
        int i = (blockIdx.x - NCLASS) * 256 + t;
        int row = i >> 6, chunk = i & 63;
        int k = chunk * 8;
        float4 a = ((const float4*)e)[i * 2];
        float4 b = ((const float4*)e)[i * 2 + 1];
        bf16x8 v;
        v[0] = (bf16)a.x; v[1] = (bf16)a.y; v[2] = (bf16)a.z; v[3] = (bf16)a.w;
        v[4] = (bf16)b.x; v[5] = (bf16)b.y; v[6] = (bf16)b.z; v[7] = (bf16)b.w;
        *(bf16x8*)&At[((k >> 5) << 13) + (row << 5) + (k & 31)] = v;
        return;
    }

    const int c = blockIdx.x;
    const int wave = t >> 6, lane = t & 63;

    const float4* src = (const float4*)(fc + (size_t)c * (KC * EDIM));
    float4* rows4 = (float4*)rows;
    #pragma unroll
    for (int i = 0; i < 5; ++i) rows4[t + i * 256] = src[t + i * 256];
    __syncthreads();

    for (int r = wave; r < KC; r += 4) {
        float s = 0.f;
        #pragma unroll
        for (int j = 0; j < 8; ++j) {
            float v = rows[r * EDIM + lane + j * 64];
            s += v * v;
        }
        #pragma unroll
        for (int off = 32; off; off >>= 1) s += __shfl_xor(s, off);
        if (lane == 0) s_invn[r] = 1.0f / fmaxf(sqrtf(s), 1e-12f);
    }
    __syncthreads();

    bf16x8* dst = (bf16x8*)(w + (size_t)c * (KC * EDIM));
    #pragma unroll
    for (int p = 0; p < 3; ++p) {
        int j = t + p * 256;
        if (j < 640) {
            int r = j >> 6;
            float inv = s_invn[r];
            float4 a = *(const float4*)(rows + j * 8);
            float4 b = *(const float4*)(rows + j * 8 + 4);
            bf16x8 v;
            v[0] = (bf16)(a.x * inv); v[1] = (bf16)(a.y * inv);
            v[2] = (bf16)(a.z * inv); v[3] = (bf16)(a.w * inv);
            v[4] = (bf16)(b.x * inv); v[5] = (bf16)(b.y * inv);
            v[6] = (bf16)(b.z * inv); v[7] = (bf16)(b.w * inv);
            dst[j] = v;
        }
    }

    float part = 0.f;
    for (int p = wave; p < 45; p += 4) {
        int i = 0, pp = p;
        while (pp >= 9 - i) { pp -= 9 - i; ++i; }
        int j = i + 1 + pp;
        float s = 0.f;
        #pragma unroll
        for (int u = 0; u < 8; ++u)
            s += rows[i * EDIM + lane + u * 64] * rows[j * EDIM + lane + u * 64];
        #pragma unroll
        for (int off = 32; off; off >>= 1) s += __shfl_xor(s, off);
        if (lane == 0) {
            float sub = 1.0f - s * s_invn[i] * s_invn[j];
            if (sub <= 0.0f) sub = 1e-10f;
            part += sqrtf(2.0f * sub);
        }
    }
    if (lane == 0) s_wsum[wave] = part;
    __syncthreads();
    if (t == 0) gram_part[c] = s_wsum[0] + s_wsum[1] + s_wsum[2] + s_wsum[3];
}

// ---------------- kernel 2: GEMM + softmax-K + fused CE partials ----------
// PACKED M: BM=80 rows = 8 classes/block. 512 threads = 8 waves, wave grid
// 1m x 8n: each wave = 80 rows x 32 batch cols (5mt x 2nt MFMA 16x16x32).
// BK=64 double-buffered (verified r7). Epilogue: per-class softmax over
// K=10 (verified r2), then per-b partial sum of exp(10h) over this block's
// 8 classes -> atomicAdd(sumexp[b]); margin applied + lab_logit stored by
// the single block owning label[b].
__global__ __launch_bounds__(512, 2) void gemm_h_kernel(
    const bf16* __restrict__ W,    // [81920][512] compact normalized centers
    const bf16* __restrict__ At,   // [16][256][32] emb bf16
    const int* __restrict__ labels,
    float* __restrict__ sumexp,    // [256] CE partial sums
    float* __restrict__ lab_logit) // [256]
{
    __shared__ bf16 Ws[2][80 * BK];   // 2 x 10 KB
    const int tid = threadIdx.x;
    const int wave = tid >> 6, lane = tid & 63;

    f32x4 acc[5][2];
    #pragma unroll
    for (int mt = 0; mt < 5; ++mt)
        #pragma unroll
        for (int nt = 0; nt < 2; ++nt)
            acc[mt][nt] = (f32x4){0.f, 0.f, 0.f, 0.f};

    const size_t g0 = (size_t)blockIdx.x * 80;   // first packed W row

    // staging: slot j in [0,640): row=j>>3, s=j&7, global chunk = s^(row&7).
    const int rA = tid >> 3, sA = tid & 7;
    const bf16* srcA = W + (g0 + rA) * EDIM + ((sA ^ (rA & 7)) << 3);
    const int rB = (512 + tid) >> 3, sB = tid & 7;
    const bf16* srcB = W + (g0 + rB) * EDIM + ((sB ^ (rB & 7)) << 3);

    const int q = lane >> 4;        // fragment chunk within 32-k
    const int q8 = q * 8;
    const int fr = lane & 15;

    // prologue: stage tile 0 into buf 0
    load_lds16(srcA, &Ws[0][wave * 512]);
    if (tid < 128) load_lds16(srcB, &Ws[0][4096 + wave * 512]);
    __syncthreads();

    for (int t = 0; t < 8; ++t) {
        const int cur = t & 1;
        if (t < 7) {
            const int kb = (t + 1) * BK;
            load_lds16(srcA + kb, &Ws[cur ^ 1][wave * 512]);
            if (tid < 128) load_lds16(srcB + kb, &Ws[cur ^ 1][4096 + wave * 512]);
        }
        #pragma unroll
        for (int kk = 0; kk < BK; kk += 32) {
            const int ccb = kk >> 3;             // 0 or 4
            bf16x8 wf[5], ef[2];
            #pragma unroll
            for (int nt = 0; nt < 2; ++nt) {
                int row = wave * 32 + nt * 16 + fr;
                ef[nt] = *(const bf16x8*)
                    &At[((t * 2 + (kk >> 5)) << 13) + (row << 5) + q8];
            }
            #pragma unroll
            for (int mt = 0; mt < 5; ++mt) {
                int row = mt * 16 + fr;
                int s = (ccb + q) ^ (row & 7);
                wf[mt] = *(const bf16x8*)&Ws[cur][row * BK + (s << 3)];
            }
            #pragma unroll
            for (int mt = 0; mt < 5; ++mt)
                #pragma unroll
                for (int nt = 0; nt < 2; ++nt)
                    acc[mt][nt] = __builtin_amdgcn_mfma_f32_16x16x32_bf16(
                        wf[mt], ef[nt], acc[mt][nt], 0, 0, 0);
        }
        __syncthreads();
    }

    // epilogue: packed row r = 16*mt + 4*quad + reg; class c = r/10.
    const int col = lane & 15;
    const int quad = lane >> 4;
    const int cb = blockIdx.x * 8;
    #pragma unroll
    for (int nt = 0; nt < 2; ++nt) {
        int b = wave * 32 + nt * 16 + col;
        float hval[8];
        #pragma unroll
        for (int cc = 0; cc < 8; ++cc) {
            float xm = -1e30f;
            #pragma unroll
            for (int mt = 0; mt < 5; ++mt) {
                if (10 * cc + 10 > 16 * mt && 10 * cc < 16 * mt + 16) { // static
                    #pragma unroll
                    for (int rg = 0; rg < 4; ++rg) {
                        int r = 16 * mt + 4 * quad + rg;
                        if (r >= 10 * cc && r < 10 * cc + 10)          // runtime
                            xm = fmaxf(xm, acc[mt][nt][rg]);
                    }
                }
            }
            xm = fmaxf(xm, __shfl_xor(xm, 16));
            xm = fmaxf(xm, __shfl_xor(xm, 32));
            float s1 = 0.f, s2 = 0.f;
            #pragma unroll
            for (int mt = 0; mt < 5; ++mt) {
                if (10 * cc + 10 > 16 * mt && 10 * cc < 16 * mt + 16) { // static
                    #pragma unroll
                    for (int rg = 0; rg < 4; ++rg) {
                        int r = 16 * mt + 4 * quad + rg;
                        if (r >= 10 * cc && r < 10 * cc + 10) {        // runtime
                            float x = acc[mt][nt][rg];
                            float e = __expf(10.0f * (x - xm));
                            s1 += e; s2 += e * x;
                        }
                    }
                }
            }
            s1 += __shfl_xor(s1, 16); s1 += __shfl_xor(s1, 32);
            s2 += __shfl_xor(s2, 16); s2 += __shfl_xor(s2, 32);
            hval[cc] = s2 / s1;
        }
        if (quad == 0) {
            // fused CE partial: logits bounded (|10h| < ~50) -> no shift
            const int lbl = labels[b];
            float ps = 0.f;
            #pragma unroll
            for (int cc = 0; cc < 8; ++cc) {
                float lg = 10.0f * hval[cc];
                if (lbl == cb + cc) {
                    lg -= 0.1f;               // LMD * MARGIN
                    lab_logit[b] = lg;        // single writer per b
                }
                ps += __expf(lg);
            }
            atomicAdd(&sumexp[b], ps);
        }
    }
}

// ---------------- kernel 3: reduce partials + combine ---------------------
__global__ __launch_bounds__(256) void final_kernel(
    const float* __restrict__ gram_part, const float* __restrict__ sumexp,
    const float* __restrict__ lab_logit, float* __restrict__ out)
{
    __shared__ float red[4];
    const int t = threadIdx.x, wave = t >> 6, lane = t & 63;
    const float4* gp4 = (const float4*)gram_part;
    float g = 0.f;
    #pragma unroll
    for (int i = 0; i < 8; ++i) {
        float4 x = gp4[t + i * 256];
        g += x.x + x.y + x.z + x.w;
    }
    float ce = logf(sumexp[t]) - lab_logit[t];   // -logp[label], no shift
    float val = ce * (1.0f / 256.0f)
              + g * (0.2f / 737280.0f);          // C*K*(K-1) = 737280
    #pragma unroll
    for (int off = 32; off; off >>= 1) val += __shfl_xor(val, off);
    if (lane == 0) red[wave] = val;
    __syncthreads();
    if (t == 0) out[0] = red[0] + red[1] + red[2] + red[3];
}

extern "C" void kernel_launch(void* const* d_in, const int* in_sizes, int n_in,
                              void* d_out, int out_size, void* d_ws, size_t ws_size,
                              hipStream_t stream) {
    const float* emb    = (const float*)d_in[0];   // [256][512]
    const int*   labels = (const int*)d_in[1];     // [256]
    const float* fc     = (const float*)d_in[2];   // [81920][512]
    float* out = (float*)d_out;

    char* ws = (char*)d_ws;
    bf16*  w         = (bf16*)ws;                        //  83886080 B
    bf16*  At        = (bf16*)(ws + 83886080);           //    262144 B
    float* gram_part = (float*)(ws + 84148224);          //     32768 B
    float* sumexp    = (float*)(ws + 84181248);          //      1024 B
    float* lab_logit = (float*)(ws + 84182272);          //      1024 B

    prep_kernel<<<NCLASS + 65, 256, 0, stream>>>(fc, w, gram_part, emb, At,
                                                 sumexp);
    gemm_h_kernel<<<81920 / 80, 512, 0, stream>>>(w, At, labels,
                                                  sumexp, lab_logit);
    final_kernel<<<1, 256, 0, stream>>>(gram_part, sumexp, lab_logit, out);
}